// Round 18
// baseline (4973.057 us; speedup 1.0000x reference)
//
#include <hip/hip_runtime.h>
#include <hip/hip_fp16.h>
#include <math.h>

#define BB 64
#define TT 32
#define ENCL 128
#define DD 800
#define TPB 1024
#define NBLK 512
#define NM 8
#define SL 100

typedef _Float16 h2 __attribute__((ext_vector_type(2)));

__device__ __forceinline__ h2 u2h(unsigned u) { union { unsigned u; h2 h; } c; c.u = u; return c.h; }
__device__ __forceinline__ unsigned pack2(float a, float b) {
    union { unsigned u; h2 h; } c; c.h[0] = (_Float16)a; c.h[1] = (_Float16)b; return c.u;
}
__device__ __forceinline__ float sigf(float x) { return 1.f / (1.f + __expf(-x)); }
__device__ __forceinline__ float wred(float v) {
#pragma unroll
    for (int o = 32; o > 0; o >>= 1) v += __shfl_xor(v, o);
    return v;
}

#if __has_builtin(__builtin_amdgcn_fdot2)
__device__ __forceinline__ float FDOT2(h2 a, h2 b, float c) { return __builtin_amdgcn_fdot2(a, b, c, false); }
#else
__device__ __forceinline__ float FDOT2(h2 a, h2 b, float c) {
    return c + (float)a[0] * (float)b[0] + (float)a[1] * (float)b[1];
}
#endif

__device__ __forceinline__ float dot8(uint4 w, uint4 x, float acc) {
    acc = FDOT2(u2h(w.x), u2h(x.x), acc);
    acc = FDOT2(u2h(w.y), u2h(x.y), acc);
    acc = FDOT2(u2h(w.z), u2h(x.z), acc);
    acc = FDOT2(u2h(w.w), u2h(x.w), acc);
    return acc;
}

// ---- volatile read: bypasses (possibly stale) L1, hits same-XCD L2 ----
__device__ __forceinline__ float vldf(const float* p) { return *(const volatile float*)p; }

// ---- 8-member group sync, FENCE-FREE (all members of row b on XCD b%8):
// payload plain stores drain to shared L2 at the __syncthreads vmcnt wait;
// release-RMW arrival + relaxed poll + watchdog. No acquire fence -> L2 stays hot. ----
__device__ __forceinline__ void gsync(unsigned* cnt, int b, unsigned target) {
    __syncthreads();
    if (threadIdx.x == 0) {
        __hip_atomic_fetch_add(&cnt[b * 32], 1u, __ATOMIC_RELEASE, __HIP_MEMORY_SCOPE_AGENT);
        int guard = 0;
        while (__hip_atomic_load(&cnt[b * 32], __ATOMIC_RELAXED, __HIP_MEMORY_SCOPE_AGENT) < target) {
            __builtin_amdgcn_s_sleep(1);
            if (++guard > (1 << 18)) break;   // deadlock -> wrong answer, never a hang
        }
    }
    __syncthreads();
}

// ---- prep: column-sliced packed weights: [m 0..7][kq 0..199][cs 0..99] uint4 ----
__global__ __launch_bounds__(256) void pack_ws(const float* __restrict__ W, uint4* __restrict__ out) {
    int i = blockIdx.x * 256 + threadIdx.x;
    if (i >= 160000) return;
    int cs = i % SL;
    int kq = (i / SL) % 200;
    int m  = i / 20000;
    const float* src = W + (size_t)(8 * kq) * 800 + SL * m + cs;
    uint4 r;
    r.x = pack2(src[0],        src[800]);
    r.y = pack2(src[2 * 800],  src[3 * 800]);
    r.z = pack2(src[4 * 800],  src[5 * 800]);
    r.w = pack2(src[6 * 800],  src[7 * 800]);
    out[i] = r;
}

__global__ __launch_bounds__(256) void pack_pairs(const float* __restrict__ in, unsigned* __restrict__ out, int n2) {
    int i = blockIdx.x * 256 + threadIdx.x;
    if (i < n2) out[i] = pack2(in[2 * i], in[2 * i + 1]);
}

__global__ __launch_bounds__(256) void pack_w1(const float* __restrict__ w1, unsigned* __restrict__ out) {
    int i = blockIdx.x * 256 + threadIdx.x;
    if (i >= 400 * 200) return;
    int c = i % 200, kp = i / 200;
    out[i] = pack2(w1[(2 * kp) * 200 + c], w1[(2 * kp + 1) * 200 + c]);
}

// ========== decoder: 8 blocks/row (b=bid&63, m=bid>>6 -> same XCD), 2 blocks/CU ==========
__global__ __launch_bounds__(TPB, 8) void decoder_kernel(
    const float* __restrict__ x, const __half* __restrict__ ench,
    const uint4* __restrict__ iws0, const uint4* __restrict__ iws1,
    const uint4* __restrict__ sws0, const uint4* __restrict__ sws1,
    const float* __restrict__ ib0, const float* __restrict__ ib1,
    const float* __restrict__ sb0, const float* __restrict__ sb1,
    const float* __restrict__ cw0, const float* __restrict__ cb0,
    const float* __restrict__ cw1, const float* __restrict__ cb1,
    const float* __restrict__ init_h, const float* __restrict__ init_c,
    __half* __restrict__ PREh, __half* __restrict__ REFh,
    float* __restrict__ PPC, float* __restrict__ PPD,
    float* __restrict__ PPhv, float* __restrict__ PPo, unsigned* __restrict__ cnt,
    const unsigned* __restrict__ w1p, const float* __restrict__ hb1,
    const float* __restrict__ hw2, const float* __restrict__ hb2,
    const float* __restrict__ hw3, const float* __restrict__ hb3,
    float* __restrict__ out)
{
    __shared__ float cwS[2][1536];
    __shared__ float cbS[2][32];
    __shared__ float HC[2][2][DD];
    __shared__ float cin[DD];
    __shared__ float hn[DD];
    __shared__ float ctxf[DD];
    __shared__ alignas(16) unsigned xh[DD];    // [0..400) ctx/ctx2 pairs, [400..800) hn/hv pairs
    __shared__ alignas(16) float pc1[NM][SL];  // GEMV partials; aliases float2[400] scratch
    __shared__ float sc[16];
    __shared__ float pw[16];
    __shared__ float pm[8], ps[8];

    const int bid = blockIdx.x;
    const int b = bid & 63;
    const int m = bid >> 6;        // 0..7 (bids b+64m -> all on XCD b%8)
    const int tid = threadIdx.x;
    const int lane = tid & 63;
    const int wv = tid >> 6;       // 16 waves
    const int d2 = tid & 511;
    const int gg = tid >> 9;
    const int kg = tid / SL;       // 0..7 (tid<800)
    const int cs = tid % SL;

    const uint4* iwS[2] = {iws0, iws1};
    const uint4* swS[2] = {sws0, sws1};
    const float* ib[2] = {ib0, ib1};
    const float* sb[2] = {sb0, sb1};
    const float* cwA[2] = {cw0, cw1};
    const float* cbA[2] = {cb0, cb1};

    for (int l2 = 0; l2 < 2; ++l2) {
        const int cin_l = l2 ? 16 : 9;
        const int nw2 = 32 * cin_l * 3;
        for (int i = tid; i < nw2; i += TPB) {
            int p = i % 3, rest = i / 3;
            int gt = rest & 3, rest2 = rest >> 2;
            int ic = rest2 % cin_l, ch = rest2 / cin_l;
            cwS[l2][(ch * cin_l + ic) * 12 + gt * 3 + p] = cwA[l2][((gt * 8 + ch) * cin_l + ic) * 3 + p];
        }
        for (int i = tid; i < 32; i += TPB) cbS[l2][i] = cbA[l2][i];
        for (int i = tid; i < DD; i += TPB) {
            HC[l2][0][i] = init_h[((size_t)l2 * BB + b) * DD + i];
            HC[l2][1][i] = init_c[((size_t)l2 * BB + b) * DD + i];
        }
    }
    __syncthreads();

    const unsigned* encb = (const unsigned*)ench + (size_t)b * ENCL * 400;
    const uint4* xh4 = (const uint4*)xh;
    const uint4* xh4h = (const uint4*)(xh + 400);
    float2* pcc = reinterpret_cast<float2*>(&pc1[0][0]);
    unsigned ep = 0;

    for (int s = 0; s < TT; ++s) {
        for (int l = 0; l < 2; ++l) {
            const int cinx = (l == 0) ? 1 : 8;
            const int cin_l = cinx + 8;
            float* PPCc = PPC + (size_t)l * (BB * NM * 804);   // depth-2 by layer parity
            float* PPDc = PPD + (size_t)l * (BB * NM * 804);
            float* PPhvc = PPhv + (size_t)l * (BB * DD);

            // ---- A: cell input ----
            if (l == 0) {
                if (tid < 100) cin[tid] = x[((size_t)b * TT + s) * 100 + tid];
            }
            __syncthreads();
            // ---- B: ConvLSTM cell (redundant) ----
            if (tid < DD) {
                const int col = tid % 10, rch = tid / 10;
                const int ch = rch & 7, r = rch >> 3;
                float g0 = cbS[l][ch], g1 = cbS[l][8 + ch], g2 = cbS[l][16 + ch], g3 = cbS[l][24 + ch];
                for (int ic = 0; ic < cin_l; ++ic) {
                    const float* zb = (ic < cinx)
                        ? ((l == 0) ? &cin[r * 10] : &cin[r * 80 + ic * 10])
                        : &HC[l][0][r * 80 + (ic - cinx) * 10];
                    float z0 = (col > 0) ? zb[col - 1] : 0.f;
                    float z1 = zb[col];
                    float z2 = (col < 9) ? zb[col + 1] : 0.f;
                    const float* wr = &cwS[l][(ch * cin_l + ic) * 12];
                    g0 += z0 * wr[0] + z1 * wr[1] + z2 * wr[2];
                    g1 += z0 * wr[3] + z1 * wr[4] + z2 * wr[5];
                    g2 += z0 * wr[6] + z1 * wr[7] + z2 * wr[8];
                    g3 += z0 * wr[9] + z1 * wr[10] + z2 * wr[11];
                }
                float c2 = sigf(g1) * HC[l][1][tid] + sigf(g0) * tanhf(g2);
                float hnv = sigf(g3) * tanhf(c2);
                hn[tid] = hnv;
                HC[l][1][tid] = c2;
            }
            __syncthreads();
            if (tid < DD) HC[l][0][tid] = hn[tid];
            if (tid < 400) xh[400 + tid] = pack2(hn[2 * tid], hn[2 * tid + 1]);
            __syncthreads();
            // ---- C: inter scores, member slice: wave wv scores enc row 16m+wv ----
            {
                const int le = 16 * m + wv;
                const uint4* erow4 = (const uint4*)(encb + (size_t)le * 400);
                float sum = dot8(erow4[lane], xh4h[lane], 0.f);
                if (lane < 36) sum = dot8(erow4[64 + lane], xh4h[64 + lane], sum);
                sum = wred(sum);
                if (lane == 0) sc[wv] = sum;
            }
            __syncthreads();
            // local softmax partial over the 16 slice scores
            float mloc = -3.0e38f;
#pragma unroll
            for (int j = 0; j < 16; ++j) mloc = fmaxf(mloc, sc[j]);
            if (tid < 16) pw[tid] = __expf(sc[tid] - mloc);
            __syncthreads();
            // ---- D: ctx partial over member's 16 rows (2 groups x 8) ----
            if (d2 < 400) {
                float a0 = 0.f, a1 = 0.f;
                const unsigned* ep2 = encb + (size_t)(16 * m + gg * 8) * 400 + d2;
#pragma unroll
                for (int k = 0; k < 8; ++k) {
                    h2 ev = u2h(ep2[(size_t)k * 400]);
                    float w = pw[gg * 8 + k];
                    a0 = fmaf(w, (float)ev[0], a0);
                    a1 = fmaf(w, (float)ev[1], a1);
                }
                if (gg == 1) pcc[d2] = make_float2(a0, a1);
                else { ctxf[2 * d2] = a0; ctxf[2 * d2 + 1] = a1; }
            }
            __syncthreads();
            {
                float* pcr = PPCc + ((size_t)b * NM + m) * 804;
                if (tid < 400) {
                    pcr[2 * tid] = ctxf[2 * tid] + pcc[tid].x;
                    pcr[2 * tid + 1] = ctxf[2 * tid + 1] + pcc[tid].y;
                } else if (tid == 400) {
                    float sl2 = 0.f;
#pragma unroll
                    for (int j = 0; j < 16; ++j) sl2 += pw[j];
                    pcr[800] = mloc;
                    pcr[801] = sl2;
                }
            }
            gsync(cnt, b, NM * (++ep));   // ctx-partial exchange (same-XCD L2)
            // ---- E: combine 8 member partials -> ctx -> xh[0..400) ----
            if (tid < 8) { pm[tid] = vldf(&PPCc[((size_t)b * NM + tid) * 804 + 800]);
                           ps[tid] = vldf(&PPCc[((size_t)b * NM + tid) * 804 + 801]); }
            __syncthreads();
            {
                float M = -3.0e38f;
#pragma unroll
                for (int j = 0; j < 8; ++j) M = fmaxf(M, pm[j]);
                if (tid < 400) {
                    float denom = 0.f, va = 0.f, vb = 0.f;
#pragma unroll
                    for (int j = 0; j < 8; ++j) {
                        float f = __expf(pm[j] - M);
                        denom += f * ps[j];
                        const float* pr = PPCc + ((size_t)b * NM + j) * 804;
                        va += f * vldf(&pr[2 * tid]);
                        vb += f * vldf(&pr[2 * tid + 1]);
                    }
                    float inv = 1.f / denom;
                    xh[tid] = pack2(va * inv, vb * inv);
                }
            }
            __syncthreads();
            // ---- F: GEMV1 column slice [100m,100m+100), k-split 8-way ----
            if (tid < 800) {
                const uint4* wp = iwS[l] + (size_t)m * 20000 + (size_t)(kg * 25) * SL + cs;
                const uint4* xv = xh4 + kg * 25;
                float acc = 0.f;
#pragma unroll 5
                for (int i = 0; i < 25; ++i)
                    acc = dot8(wp[(size_t)i * SL], xv[i], acc);
                pc1[kg][cs] = acc;
            }
            __syncthreads();
            if (tid < SL) {
                float v = pc1[0][tid] + pc1[1][tid] + pc1[2][tid] + pc1[3][tid]
                        + pc1[4][tid] + pc1[5][tid] + pc1[6][tid] + pc1[7][tid]
                        + ib[l][SL * m + tid];
                v = tanhf(v);
                PREh[((size_t)(l * BB + b) * TT + s) * DD + SL * m + tid] = (__half)v;
                if (s == 0) REFh[((size_t)(l * BB + b) * TT + 0) * DD + SL * m + tid] = (__half)v;
                PPhvc[(size_t)b * DD + SL * m + tid] = v;
            }

            if (s == 0) {
                if (l == 0) {
                    gsync(cnt, b, NM * (++ep));
                    if (tid < DD) cin[tid] = vldf(&PPhvc[(size_t)b * DD + tid]);   // layer-1 input
                    __syncthreads();
                }
            } else {
                gsync(cnt, b, NM * (++ep));   // hv exchange
                if (tid < 400) {
                    float a = vldf(&PPhvc[(size_t)b * DD + 2 * tid]);
                    float bb2 = vldf(&PPhvc[(size_t)b * DD + 2 * tid + 1]);
                    xh[400 + tid] = pack2(a, bb2);   // query + GEMV2 hv half
                }
                __syncthreads();
                // ---- G: self scores, member slice: wave wv -> t' = m + 8*wv (wv<4) ----
                const int nt = (s > m) ? ((s - m + 7) >> 3) : 0;
                if (wv < 4) {
                    const int tp = m + 8 * wv;
                    float sum = 0.f;
                    if (tp < s) {
                        const uint4* pr4 = (const uint4*)((const unsigned*)PREh
                            + ((size_t)(l * BB + b) * TT + tp) * 400);
                        sum = dot8(pr4[lane], xh4h[lane], 0.f);
                        if (lane < 36) sum = dot8(pr4[64 + lane], xh4h[64 + lane], sum);
                        sum = wred(sum);
                    }
                    if (lane == 0) sc[wv] = sum;
                }
                __syncthreads();
                float ml2 = -3.0e38f;
                for (int j = 0; j < nt; ++j) ml2 = fmaxf(ml2, sc[j]);
                if (tid < 4) pw[tid] = (tid < nt) ? __expf(sc[tid] - ml2) : 0.f;
                __syncthreads();
                // ---- H: ctx2 partial over member's rows (2 groups x 2) ----
                if (d2 < 400) {
                    float a0 = 0.f, a1 = 0.f;
#pragma unroll
                    for (int w = 0; w < 2; ++w) {
                        int ww = gg + 2 * w;
                        if (ww < nt) {
                            const unsigned* rr = (const unsigned*)REFh
                                + ((size_t)(l * BB + b) * TT + (m + 8 * ww)) * 400 + d2;
                            h2 rv = u2h(rr[0]);
                            float wgt = pw[ww];
                            a0 = fmaf(wgt, (float)rv[0], a0);
                            a1 = fmaf(wgt, (float)rv[1], a1);
                        }
                    }
                    if (gg == 1) pcc[d2] = make_float2(a0, a1);
                    else { ctxf[2 * d2] = a0; ctxf[2 * d2 + 1] = a1; }
                }
                __syncthreads();
                {
                    float* pdr = PPDc + ((size_t)b * NM + m) * 804;
                    if (tid < 400) {
                        pdr[2 * tid] = ctxf[2 * tid] + pcc[tid].x;
                        pdr[2 * tid + 1] = ctxf[2 * tid + 1] + pcc[tid].y;
                    } else if (tid == 400) {
                        float sl2 = pw[0] + pw[1] + pw[2] + pw[3];
                        pdr[800] = (nt > 0) ? ml2 : -3.0e38f;
                        pdr[801] = sl2;
                    }
                }
                gsync(cnt, b, NM * (++ep));   // ctx2-partial exchange
                // ---- I: combine -> ctx2 -> xh[0..400) ----
                if (tid < 8) { pm[tid] = vldf(&PPDc[((size_t)b * NM + tid) * 804 + 800]);
                               ps[tid] = vldf(&PPDc[((size_t)b * NM + tid) * 804 + 801]); }
                __syncthreads();
                {
                    float M = -3.0e38f;
#pragma unroll
                    for (int j = 0; j < 8; ++j) M = fmaxf(M, pm[j]);
                    if (tid < 400) {
                        float denom = 0.f, va = 0.f, vb = 0.f;
#pragma unroll
                        for (int j = 0; j < 8; ++j) {
                            float f = __expf(pm[j] - M);
                            denom += f * ps[j];
                            const float* pr = PPDc + ((size_t)b * NM + j) * 804;
                            va += f * vldf(&pr[2 * tid]);
                            vb += f * vldf(&pr[2 * tid + 1]);
                        }
                        float inv = 1.f / denom;
                        xh[tid] = pack2(va * inv, vb * inv);
                    }
                }
                __syncthreads();
                // ---- J: GEMV2 column slice, k-split 8-way ----
                if (tid < 800) {
                    const uint4* wp = swS[l] + (size_t)m * 20000 + (size_t)(kg * 25) * SL + cs;
                    const uint4* xv = xh4 + kg * 25;
                    float acc = 0.f;
#pragma unroll 5
                    for (int i = 0; i < 25; ++i)
                        acc = dot8(wp[(size_t)i * SL], xv[i], acc);
                    pc1[kg][cs] = acc;
                }
                __syncthreads();
                if (tid < SL) {
                    float v = pc1[0][tid] + pc1[1][tid] + pc1[2][tid] + pc1[3][tid]
                            + pc1[4][tid] + pc1[5][tid] + pc1[6][tid] + pc1[7][tid]
                            + sb[l][SL * m + tid];
                    v = tanhf(v);
                    REFh[((size_t)(l * BB + b) * TT + s) * DD + SL * m + tid] = (__half)v;
                    if (l == 0) PPo[(size_t)b * DD + SL * m + tid] = v;
                }
                if (l == 0) {
                    gsync(cnt, b, NM * (++ep));   // layer-0 out exchange
                    if (tid < DD) cin[tid] = vldf(&PPo[(size_t)b * DD + tid]);
                    __syncthreads();
                }
            }
        }
    }

    gsync(cnt, b, NM * (++ep));   // all REFh slices visible (same-XCD L2) for head

    // ====== head MLP: member m handles t in [4m, 4m+4) ======
    unsigned* r8 = reinterpret_cast<unsigned*>(&HC[0][0][0]);   // 4 x 400 u32
    float* v1s = &cwS[0][0];                                     // 800 f32
    float* v2s = &cwS[0][0] + 800;                               // 200 f32
    const unsigned* refu = (const unsigned*)REFh + (((size_t)BB + b) * TT) * 400;
    for (int i = tid; i < 4 * 400; i += TPB)
        r8[i] = refu[(size_t)(m * 4 + i / 400) * 400 + (i % 400)];
    __syncthreads();
    for (int o = tid; o < 800; o += TPB) {
        int tr = o / 200, c = o % 200;
        float acc = hb1[c];
        const unsigned* rrow = &r8[tr * 400];
#pragma unroll 8
        for (int kp = 0; kp < 400; ++kp)
            acc = FDOT2(u2h(w1p[kp * 200 + c]), u2h(rrow[kp]), acc);
        v1s[o] = fmaxf(acc, 0.f);
    }
    __syncthreads();
    for (int o = tid; o < 200; o += TPB) {
        int tr = o / 50, c = o % 50;
        float acc = hb2[c];
#pragma unroll 4
        for (int k = 0; k < 200; ++k) acc = fmaf(v1s[tr * 200 + k], hw2[k * 50 + c], acc);
        v2s[o] = fmaxf(acc, 0.f);
    }
    __syncthreads();
    for (int o = tid; o < 12; o += TPB) {
        int tr = o / 3, oo = o % 3;
        float acc = hb3[oo];
        for (int k = 0; k < 50; ++k) acc = fmaf(v2s[tr * 50 + k], hw3[k * 3 + oo], acc);
        out[((size_t)b * TT + m * 4 + tr) * 3 + oo] = acc;
    }
}

extern "C" void kernel_launch(void* const* d_in, const int* in_sizes, int n_in,
                              void* d_out, int out_size, void* d_ws, size_t ws_size,
                              hipStream_t stream)
{
    const float* x_flat = (const float*)d_in[0];
    const float* enc    = (const float*)d_in[1];
    const float* init_h = (const float*)d_in[2];
    const float* init_c = (const float*)d_in[3];
    const float* cw0 = (const float*)d_in[4];
    const float* cb0 = (const float*)d_in[5];
    const float* cw1 = (const float*)d_in[6];
    const float* cb1 = (const float*)d_in[7];
    const float* iw0 = (const float*)d_in[8];
    const float* ib0 = (const float*)d_in[9];
    const float* iw1 = (const float*)d_in[10];
    const float* ib1 = (const float*)d_in[11];
    const float* sw0 = (const float*)d_in[12];
    const float* sb0 = (const float*)d_in[13];
    const float* sw1 = (const float*)d_in[14];
    const float* sb1 = (const float*)d_in[15];
    const float* hw1 = (const float*)d_in[16];
    const float* hb1 = (const float*)d_in[17];
    const float* hw2 = (const float*)d_in[18];
    const float* hb2 = (const float*)d_in[19];
    const float* hw3 = (const float*)d_in[20];
    const float* hb3 = (const float*)d_in[21];
    float* out = (float*)d_out;

    char* p = (char*)d_ws;
    uint4* iws0 = (uint4*)p; p += (size_t)160000 * 16;   // 2.56 MB each
    uint4* iws1 = (uint4*)p; p += (size_t)160000 * 16;
    uint4* sws0 = (uint4*)p; p += (size_t)160000 * 16;
    uint4* sws1 = (uint4*)p; p += (size_t)160000 * 16;
    __half* ench = (__half*)p; p += (size_t)BB * ENCL * DD * 2;        // 13.1 MB
    unsigned* w1p = (unsigned*)p; p += (size_t)400 * 200 * 4;          // 320 KB
    __half* PREh = (__half*)p; p += (size_t)2 * BB * TT * DD * 2;      // 6.55 MB
    __half* REFh = (__half*)p; p += (size_t)2 * BB * TT * DD * 2;      // 6.55 MB
    float* PPC  = (float*)p; p += (size_t)2 * BB * NM * 804 * 4;       // 1.65 MB
    float* PPD  = (float*)p; p += (size_t)2 * BB * NM * 804 * 4;       // 1.65 MB
    float* PPhv = (float*)p; p += (size_t)2 * BB * DD * 4;             // 410 KB
    float* PPo  = (float*)p; p += (size_t)BB * DD * 4;                 // 205 KB
    unsigned* cnt = (unsigned*)p; p += (size_t)BB * 32 * 4;            // 8 KB

    (void)hipMemsetAsync(cnt, 0, (size_t)BB * 32 * 4, stream);

    pack_ws<<<625, 256, 0, stream>>>(iw0, iws0);
    pack_ws<<<625, 256, 0, stream>>>(iw1, iws1);
    pack_ws<<<625, 256, 0, stream>>>(sw0, sws0);
    pack_ws<<<625, 256, 0, stream>>>(sw1, sws1);
    pack_pairs<<<12800, 256, 0, stream>>>(enc, (unsigned*)ench, BB * ENCL * DD / 2);
    pack_w1<<<313, 256, 0, stream>>>(hw1, w1p);

    decoder_kernel<<<NBLK, TPB, 0, stream>>>(
        x_flat, ench, iws0, iws1, sws0, sws1, ib0, ib1, sb0, sb1,
        cw0, cb0, cw1, cb1, init_h, init_c, PREh, REFh,
        PPC, PPD, PPhv, PPo, cnt,
        w1p, hb1, hw2, hb2, hw3, hb3, out);
}

// Round 19
// 4139.792 us; speedup vs baseline: 1.2013x; 1.2013x over previous
//
#include <hip/hip_runtime.h>
#include <hip/hip_fp16.h>
#include <math.h>

#define BB 64
#define TT 32
#define ENCL 128
#define DD 800
#define TPB 1024
#define NBLK 256
#define NM 4
#define SL 200

typedef _Float16 h2 __attribute__((ext_vector_type(2)));

__device__ __forceinline__ h2 u2h(unsigned u) { union { unsigned u; h2 h; } c; c.u = u; return c.h; }
__device__ __forceinline__ unsigned pack2(float a, float b) {
    union { unsigned u; h2 h; } c; c.h[0] = (_Float16)a; c.h[1] = (_Float16)b; return c.u;
}
__device__ __forceinline__ float sigf(float x) { return 1.f / (1.f + __expf(-x)); }
__device__ __forceinline__ float wred(float v) {
#pragma unroll
    for (int o = 32; o > 0; o >>= 1) v += __shfl_xor(v, o);
    return v;
}
__device__ __forceinline__ float wmax(float v) {
#pragma unroll
    for (int o = 32; o > 0; o >>= 1) v = fmaxf(v, __shfl_xor(v, o));
    return v;
}

#if __has_builtin(__builtin_amdgcn_fdot2)
__device__ __forceinline__ float FDOT2(h2 a, h2 b, float c) { return __builtin_amdgcn_fdot2(a, b, c, false); }
#else
__device__ __forceinline__ float FDOT2(h2 a, h2 b, float c) {
    return c + (float)a[0] * (float)b[0] + (float)a[1] * (float)b[1];
}
#endif

__device__ __forceinline__ float dot8(uint4 w, uint4 x, float acc) {
    acc = FDOT2(u2h(w.x), u2h(x.x), acc);
    acc = FDOT2(u2h(w.y), u2h(x.y), acc);
    acc = FDOT2(u2h(w.z), u2h(x.z), acc);
    acc = FDOT2(u2h(w.w), u2h(x.w), acc);
    return acc;
}

// ---- volatile read: bypasses (possibly stale) L1, hits same-XCD L2 ----
__device__ __forceinline__ float vld(const float* p) { return *(const volatile float*)p; }

// ---- 4-member group sync, fence-free (same-XCD L2 coherence; members of row b
// are bids b+64m -> all on XCD b%8). Release-RMW arrival + relaxed poll + watchdog. ----
__device__ __forceinline__ void gsync(unsigned* cnt, int b, unsigned target) {
    __syncthreads();
    if (threadIdx.x == 0) {
        __hip_atomic_fetch_add(&cnt[b * 32], 1u, __ATOMIC_RELEASE, __HIP_MEMORY_SCOPE_AGENT);
        int guard = 0;
        while (__hip_atomic_load(&cnt[b * 32], __ATOMIC_RELAXED, __HIP_MEMORY_SCOPE_AGENT) < target) {
            __builtin_amdgcn_s_sleep(1);
            if (++guard > (1 << 18)) break;
        }
    }
    __syncthreads();
}

// ---- prep: column-sliced packed weights: [m 0..3][kq 0..199][cs 0..199] uint4 ----
__global__ __launch_bounds__(256) void pack_ws(const float* __restrict__ W, uint4* __restrict__ out) {
    int i = blockIdx.x * 256 + threadIdx.x;
    if (i >= 160000) return;
    int cs = i % SL;
    int kq = (i / SL) % 200;
    int m  = i / 40000;
    const float* src = W + (size_t)(8 * kq) * 800 + SL * m + cs;
    uint4 r;
    r.x = pack2(src[0],        src[800]);
    r.y = pack2(src[2 * 800],  src[3 * 800]);
    r.z = pack2(src[4 * 800],  src[5 * 800]);
    r.w = pack2(src[6 * 800],  src[7 * 800]);
    out[i] = r;
}

__global__ __launch_bounds__(256) void pack_pairs(const float* __restrict__ in, unsigned* __restrict__ out, int n2) {
    int i = blockIdx.x * 256 + threadIdx.x;
    if (i < n2) out[i] = pack2(in[2 * i], in[2 * i + 1]);
}

__global__ __launch_bounds__(256) void pack_w1(const float* __restrict__ w1, unsigned* __restrict__ out) {
    int i = blockIdx.x * 256 + threadIdx.x;
    if (i >= 400 * 200) return;
    int c = i % 200, kp = i / 200;
    out[i] = pack2(w1[(2 * kp) * 200 + c], w1[(2 * kp + 1) * 200 + c]);
}

// ========== decoder: 4 blocks per batch row (b = bid&63, m = bid>>6), 1 block/CU ==========
__global__ __launch_bounds__(TPB, 4) void decoder_kernel(
    const float* __restrict__ x, const __half* __restrict__ ench,
    const uint4* __restrict__ iws0, const uint4* __restrict__ iws1,
    const uint4* __restrict__ sws0, const uint4* __restrict__ sws1,
    const float* __restrict__ ib0, const float* __restrict__ ib1,
    const float* __restrict__ sb0, const float* __restrict__ sb1,
    const float* __restrict__ cw0, const float* __restrict__ cb0,
    const float* __restrict__ cw1, const float* __restrict__ cb1,
    const float* __restrict__ init_h, const float* __restrict__ init_c,
    __half* __restrict__ PREh, __half* __restrict__ REFh,
    float* __restrict__ PP, unsigned* __restrict__ cnt,
    const unsigned* __restrict__ w1p, const float* __restrict__ hb1,
    const float* __restrict__ hw2, const float* __restrict__ hb2,
    const float* __restrict__ hw3, const float* __restrict__ hb3,
    float* __restrict__ out)
{
    __shared__ float cwS[2][1536];
    __shared__ float cbS[2][32];
    __shared__ float HC[2][2][DD];
    __shared__ float cin[DD];
    __shared__ float hn[DD];
    __shared__ float ctxf[DD];
    __shared__ alignas(16) unsigned xh[DD];    // [0..399] ctx/ctx2 pairs, [400..799] hn/hv pairs
    __shared__ alignas(16) float pc1[NM][SL];  // GEMV k-group partials; float2[400] scratch
    __shared__ float sc[128];
    __shared__ float pw[128];

    const int bid = blockIdx.x;
    const int b = bid & 63;
    const int m = bid >> 6;        // 0..3 (all members of b share XCD b%8)
    const int tid = threadIdx.x;
    const int lane = tid & 63;
    const int wv = tid >> 6;       // 16 waves
    const int d2 = tid & 511;
    const int gg = tid >> 9;
    const int kg = tid / SL;       // 0..3 for tid<800
    const int cs = tid % SL;

    const uint4* iwS[2] = {iws0, iws1};
    const uint4* swS[2] = {sws0, sws1};
    const float* ib[2] = {ib0, ib1};
    const float* sb[2] = {sb0, sb1};
    const float* cwA[2] = {cw0, cw1};
    const float* cbA[2] = {cb0, cb1};

    for (int l2 = 0; l2 < 2; ++l2) {
        const int cin_l = l2 ? 16 : 9;
        const int nw2 = 32 * cin_l * 3;
        for (int i = tid; i < nw2; i += TPB) {
            int p = i % 3, rest = i / 3;
            int gt = rest & 3, rest2 = rest >> 2;
            int ic = rest2 % cin_l, ch = rest2 / cin_l;
            cwS[l2][(ch * cin_l + ic) * 12 + gt * 3 + p] = cwA[l2][((gt * 8 + ch) * cin_l + ic) * 3 + p];
        }
        for (int i = tid; i < 32; i += TPB) cbS[l2][i] = cbA[l2][i];
        for (int i = tid; i < DD; i += TPB) {
            HC[l2][0][i] = init_h[((size_t)l2 * BB + b) * DD + i];
            HC[l2][1][i] = init_c[((size_t)l2 * BB + b) * DD + i];
        }
    }
    __syncthreads();

    const unsigned* encb = (const unsigned*)ench + (size_t)b * ENCL * 400;
    const uint4* xh4 = (const uint4*)xh;
    const uint4* xh4h = (const uint4*)(xh + 400);
    float2* pcc = reinterpret_cast<float2*>(&pc1[0][0]);
    unsigned ep = 0;

    for (int s = 0; s < TT; ++s) {
        for (int l = 0; l < 2; ++l) {
            const int cinx = (l == 0) ? 1 : 8;
            const int cin_l = cinx + 8;
            const int st = 2 * s + l;
            float* PPhv = PP + (size_t)(st & 3) * (BB * DD);          // 4-deep rotation
            float* PPo  = PP + (size_t)(4 + (s & 1)) * (BB * DD);     // out exchange (l=0 only)

            // ---- A: cell input ----
            if (l == 0) {
                if (tid < 100) cin[tid] = x[((size_t)b * TT + s) * 100 + tid];
            }
            __syncthreads();
            // ---- B: ConvLSTM cell (redundant across members) ----
            if (tid < DD) {
                const int col = tid % 10, rch = tid / 10;
                const int ch = rch & 7, r = rch >> 3;
                float g0 = cbS[l][ch], g1 = cbS[l][8 + ch], g2 = cbS[l][16 + ch], g3 = cbS[l][24 + ch];
                for (int ic = 0; ic < cin_l; ++ic) {
                    const float* zb = (ic < cinx)
                        ? ((l == 0) ? &cin[r * 10] : &cin[r * 80 + ic * 10])
                        : &HC[l][0][r * 80 + (ic - cinx) * 10];
                    float z0 = (col > 0) ? zb[col - 1] : 0.f;
                    float z1 = zb[col];
                    float z2 = (col < 9) ? zb[col + 1] : 0.f;
                    const float* wr = &cwS[l][(ch * cin_l + ic) * 12];
                    g0 += z0 * wr[0] + z1 * wr[1] + z2 * wr[2];
                    g1 += z0 * wr[3] + z1 * wr[4] + z2 * wr[5];
                    g2 += z0 * wr[6] + z1 * wr[7] + z2 * wr[8];
                    g3 += z0 * wr[9] + z1 * wr[10] + z2 * wr[11];
                }
                float c2 = sigf(g1) * HC[l][1][tid] + sigf(g0) * tanhf(g2);
                float hnv = sigf(g3) * tanhf(c2);
                hn[tid] = hnv;
                HC[l][1][tid] = c2;
            }
            __syncthreads();
            if (tid < DD) HC[l][0][tid] = hn[tid];
            if (tid < 400) xh[400 + tid] = pack2(hn[2 * tid], hn[2 * tid + 1]);
            __syncthreads();
            // ---- C: inter-attn scores (redundant), 16 waves x 8 enc rows ----
#pragma unroll
            for (int r8 = 0; r8 < 8; ++r8) {
                const int le = wv * 8 + r8;
                const uint4* erow4 = (const uint4*)(encb + (size_t)le * 400);
                float sum = dot8(erow4[lane], xh4h[lane], 0.f);
                if (lane < 36) sum = dot8(erow4[64 + lane], xh4h[64 + lane], sum);
                sum = wred(sum);
                if (lane == 0) sc[le] = sum;
            }
            __syncthreads();
            // ---- D: softmax over 128 ----
            if (wv == 0) {
                float v0 = sc[lane], v1 = sc[64 + lane];
                float mm = wmax(fmaxf(v0, v1));
                float e0 = __expf(v0 - mm), e1 = __expf(v1 - mm);
                float S = wred(e0 + e1);
                float inv = 1.f / S;
                pw[lane] = e0 * inv;
                pw[64 + lane] = e1 * inv;
            }
            __syncthreads();
            // ---- E: ctx (redundant), le halves split across 2 thread groups ----
            if (d2 < 400) {
                float a0 = 0.f, a1 = 0.f;
                const unsigned* ep2 = encb + (size_t)(gg * 64) * 400 + d2;
#pragma unroll 8
                for (int k = 0; k < 64; ++k) {
                    h2 ev = u2h(ep2[(size_t)k * 400]);
                    float w = pw[gg * 64 + k];
                    a0 = fmaf(w, (float)ev[0], a0);
                    a1 = fmaf(w, (float)ev[1], a1);
                }
                if (gg == 1) pcc[d2] = make_float2(a0, a1);
                else { ctxf[2 * d2] = a0; ctxf[2 * d2 + 1] = a1; }
            }
            __syncthreads();
            if (tid < 400) xh[tid] = pack2(ctxf[2 * tid] + pcc[tid].x, ctxf[2 * tid + 1] + pcc[tid].y);
            __syncthreads();
            // ---- F: GEMV1 column slice [200m,200m+200), k-grouped 4-way ----
            if (tid < 800) {
                const uint4* wp = iwS[l] + (size_t)m * 40000 + (size_t)(kg * 50) * SL + cs;
                const uint4* xv = xh4 + kg * 50;
                float acc = 0.f;
#pragma unroll 10
                for (int i = 0; i < 50; ++i)
                    acc = dot8(wp[(size_t)i * SL], xv[i], acc);
                pc1[kg][cs] = acc;
            }
            __syncthreads();
            if (tid < SL) {
                float v = pc1[0][tid] + pc1[1][tid] + pc1[2][tid] + pc1[3][tid]
                        + ib[l][SL * m + tid];
                v = tanhf(v);
                PREh[((size_t)(l * BB + b) * TT + s) * DD + SL * m + tid] = (__half)v;
                if (s == 0) REFh[((size_t)(l * BB + b) * TT + 0) * DD + SL * m + tid] = (__half)v;
                PPhv[(size_t)b * DD + SL * m + tid] = v;
            }

            if (s == 0) {
                if (l == 0) {
                    gsync(cnt, b, NM * (++ep));
                    if (tid < DD) cin[tid] = vld(&PPhv[(size_t)b * DD + tid]);   // layer-1 input
                    __syncthreads();
                }
                // l==1, s==0: slice writes done; later readers ordered via later syncs
            } else {
                gsync(cnt, b, NM * (++ep));   // hv exchange
                if (tid < 400) {
                    float a = vld(&PPhv[(size_t)b * DD + 2 * tid]);
                    float bb2 = vld(&PPhv[(size_t)b * DD + 2 * tid + 1]);
                    xh[400 + tid] = pack2(a, bb2);   // query + GEMV2 hv part
                }
                __syncthreads();
                // ---- G: self-attn scores over full rows (redundant) ----
                for (int tp = wv; tp < s; tp += 16) {
                    const uint4* pr4 = (const uint4*)((const unsigned*)PREh
                        + ((size_t)(l * BB + b) * TT + tp) * 400);
                    float sum = dot8(pr4[lane], xh4h[lane], 0.f);
                    if (lane < 36) sum = dot8(pr4[64 + lane], xh4h[64 + lane], sum);
                    sum = wred(sum);
                    if (lane == 0) sc[tp] = sum;
                }
                __syncthreads();
                // ---- H: softmax over s ----
                if (wv == 0) {
                    float v = (lane < s) ? sc[lane] : -3.0e38f;
                    float mm = wmax(v);
                    float e = (lane < s) ? __expf(v - mm) : 0.f;
                    float S = wred(e);
                    if (lane < 32) pw[lane] = e / S;
                }
                __syncthreads();
                // ---- I: ctx2 (redundant), t' parity split across 2 groups ----
                if (d2 < 400) {
                    float a0 = 0.f, a1 = 0.f;
                    const unsigned* rr = (const unsigned*)REFh + ((size_t)(l * BB + b) * TT) * 400 + d2;
#pragma unroll 4
                    for (int tp = gg; tp < s; tp += 2) {
                        h2 rv = u2h(rr[(size_t)tp * 400]);
                        float w = pw[tp];
                        a0 = fmaf(w, (float)rv[0], a0);
                        a1 = fmaf(w, (float)rv[1], a1);
                    }
                    if (gg == 1) pcc[d2] = make_float2(a0, a1);
                    else { ctxf[2 * d2] = a0; ctxf[2 * d2 + 1] = a1; }
                }
                __syncthreads();
                if (tid < 400) xh[tid] = pack2(ctxf[2 * tid] + pcc[tid].x, ctxf[2 * tid + 1] + pcc[tid].y);
                __syncthreads();
                // ---- J: GEMV2 column slice, full k ----
                if (tid < 800) {
                    const uint4* wp = swS[l] + (size_t)m * 40000 + (size_t)(kg * 50) * SL + cs;
                    const uint4* xv = xh4 + kg * 50;
                    float acc = 0.f;
#pragma unroll 10
                    for (int i = 0; i < 50; ++i)
                        acc = dot8(wp[(size_t)i * SL], xv[i], acc);
                    pc1[kg][cs] = acc;
                }
                __syncthreads();
                if (tid < SL) {
                    float v = pc1[0][tid] + pc1[1][tid] + pc1[2][tid] + pc1[3][tid]
                            + sb[l][SL * m + tid];
                    v = tanhf(v);
                    REFh[((size_t)(l * BB + b) * TT + s) * DD + SL * m + tid] = (__half)v;
                    if (l == 0) PPo[(size_t)b * DD + SL * m + tid] = v;
                }
                if (l == 0) {
                    gsync(cnt, b, NM * (++ep));   // layer-0 out exchange
                    if (tid < DD) cin[tid] = vld(&PPo[(size_t)b * DD + tid]);
                    __syncthreads();
                }
            }
        }
    }

    gsync(cnt, b, NM * (++ep));   // all REFh slices visible (same-XCD L2) for head

    // ====== head MLP: member m handles t in [8m, 8m+8) ======
    unsigned* r8 = reinterpret_cast<unsigned*>(&HC[0][0][0]);   // 8 x 400 u32
    float* v1s = &cwS[0][0];                                     // 1600 f32
    float* v2s = &cwS[0][0] + 1600;                              // 400 f32
    const unsigned* refu = (const unsigned*)REFh + (((size_t)BB + b) * TT) * 400;
    for (int i = tid; i < 8 * 400; i += TPB)
        r8[i] = refu[(size_t)(m * 8 + i / 400) * 400 + (i % 400)];
    __syncthreads();
    for (int o = tid; o < 1600; o += TPB) {
        int tr = o / 200, c = o % 200;
        float acc = hb1[c];
        const unsigned* rrow = &r8[tr * 400];
#pragma unroll 8
        for (int kp = 0; kp < 400; ++kp)
            acc = FDOT2(u2h(w1p[kp * 200 + c]), u2h(rrow[kp]), acc);
        v1s[o] = fmaxf(acc, 0.f);
    }
    __syncthreads();
    for (int o = tid; o < 400; o += TPB) {
        int tr = o / 50, c = o % 50;
        float acc = hb2[c];
#pragma unroll 4
        for (int k = 0; k < 200; ++k) acc = fmaf(v1s[tr * 200 + k], hw2[k * 50 + c], acc);
        v2s[o] = fmaxf(acc, 0.f);
    }
    __syncthreads();
    for (int o = tid; o < 24; o += TPB) {
        int tr = o / 3, oo = o % 3;
        float acc = hb3[oo];
        for (int k = 0; k < 50; ++k) acc = fmaf(v2s[tr * 50 + k], hw3[k * 3 + oo], acc);
        out[((size_t)b * TT + m * 8 + tr) * 3 + oo] = acc;
    }
}

extern "C" void kernel_launch(void* const* d_in, const int* in_sizes, int n_in,
                              void* d_out, int out_size, void* d_ws, size_t ws_size,
                              hipStream_t stream)
{
    const float* x_flat = (const float*)d_in[0];
    const float* enc    = (const float*)d_in[1];
    const float* init_h = (const float*)d_in[2];
    const float* init_c = (const float*)d_in[3];
    const float* cw0 = (const float*)d_in[4];
    const float* cb0 = (const float*)d_in[5];
    const float* cw1 = (const float*)d_in[6];
    const float* cb1 = (const float*)d_in[7];
    const float* iw0 = (const float*)d_in[8];
    const float* ib0 = (const float*)d_in[9];
    const float* iw1 = (const float*)d_in[10];
    const float* ib1 = (const float*)d_in[11];
    const float* sw0 = (const float*)d_in[12];
    const float* sb0 = (const float*)d_in[13];
    const float* sw1 = (const float*)d_in[14];
    const float* sb1 = (const float*)d_in[15];
    const float* hw1 = (const float*)d_in[16];
    const float* hb1 = (const float*)d_in[17];
    const float* hw2 = (const float*)d_in[18];
    const float* hb2 = (const float*)d_in[19];
    const float* hw3 = (const float*)d_in[20];
    const float* hb3 = (const float*)d_in[21];
    float* out = (float*)d_out;

    char* p = (char*)d_ws;
    uint4* iws0 = (uint4*)p; p += (size_t)160000 * 16;   // 2.56 MB each
    uint4* iws1 = (uint4*)p; p += (size_t)160000 * 16;
    uint4* sws0 = (uint4*)p; p += (size_t)160000 * 16;
    uint4* sws1 = (uint4*)p; p += (size_t)160000 * 16;
    __half* ench = (__half*)p; p += (size_t)BB * ENCL * DD * 2;        // 13.1 MB
    unsigned* w1p = (unsigned*)p; p += (size_t)400 * 200 * 4;          // 320 KB
    __half* PREh = (__half*)p; p += (size_t)2 * BB * TT * DD * 2;      // 6.55 MB
    __half* REFh = (__half*)p; p += (size_t)2 * BB * TT * DD * 2;      // 6.55 MB
    float* PP    = (float*)p; p += (size_t)6 * BB * DD * 4;            // 1.23 MB (4 hv + 2 out)
    unsigned* cnt = (unsigned*)p; p += (size_t)BB * 32 * 4;            // 8 KB

    (void)hipMemsetAsync(cnt, 0, (size_t)BB * 32 * 4, stream);

    pack_ws<<<625, 256, 0, stream>>>(iw0, iws0);
    pack_ws<<<625, 256, 0, stream>>>(iw1, iws1);
    pack_ws<<<625, 256, 0, stream>>>(sw0, sws0);
    pack_ws<<<625, 256, 0, stream>>>(sw1, sws1);
    pack_pairs<<<12800, 256, 0, stream>>>(enc, (unsigned*)ench, BB * ENCL * DD / 2);
    pack_w1<<<313, 256, 0, stream>>>(hw1, w1p);

    decoder_kernel<<<NBLK, TPB, 0, stream>>>(
        x_flat, ench, iws0, iws1, sws0, sws1, ib0, ib1, sb0, sb1,
        cw0, cb0, cw1, cb1, init_h, init_c, PREh, REFh, PP, cnt,
        w1p, hb1, hw2, hb2, hw3, hb3, out);
}